// Round 1
// 251.975 us; speedup vs baseline: 1.0706x; 1.0706x over previous
//
#include <hip/hip_runtime.h>
#include <hip/hip_bf16.h>
#include <math.h>

#define EPT 16      // edges per thread in scatter kernel
#define BCAP 16384  // bucket capacity (avg ~8.2k for uniform random, +90 sigma)

typedef _Float16 half8 __attribute__((ext_vector_type(8)));
typedef _Float16 half2v __attribute__((ext_vector_type(2)));
typedef float f32x4 __attribute__((ext_vector_type(4)));

__device__ __forceinline__ unsigned short f16r(float f) {
    _Float16 h = (_Float16)f;
    return __builtin_bit_cast(unsigned short, h);
}
__device__ __forceinline__ half2v h2(unsigned u) {
    return __builtin_bit_cast(half2v, u);
}

// ---------------- CSR build: single-pass 512-node bucket binning ----------------
// bucket b = dst >> 9; edge record = (src << 9) | (dst & 511)  [needs N <= 131072]

__global__ void scat1_kernel(const int* __restrict__ src, const int* __restrict__ dst,
                             int* __restrict__ cntg, unsigned* __restrict__ ebuf, int E) {
    __shared__ int lh[256];
    __shared__ int lbase[256];
    int tid = threadIdx.x;
    lh[tid] = 0;
    __syncthreads();
    int base = blockIdx.x * (256 * EPT);
    int ds[EPT], ss[EPT];
#pragma unroll
    for (int k = 0; k < EPT; ++k) {
        int e = base + k * 256 + tid;
        ds[k] = (e < E) ? dst[e] : -1;
        ss[k] = (e < E) ? src[e] : 0;
    }
#pragma unroll
    for (int k = 0; k < EPT; ++k) {
        if (ds[k] >= 0) atomicAdd(&lh[ds[k] >> 9], 1);
    }
    __syncthreads();
    if (lh[tid] > 0) lbase[tid] = atomicAdd(&cntg[tid], lh[tid]);
    lh[tid] = 0;
    __syncthreads();
#pragma unroll
    for (int k = 0; k < EPT; ++k) {
        if (ds[k] >= 0) {
            int b = ds[k] >> 9;
            int pos = lbase[b] + atomicAdd(&lh[b], 1);
            ebuf[(size_t)b * BCAP + pos] = ((unsigned)ss[k] << 9) | (unsigned)(ds[k] & 511);
        }
    }
}

__global__ void build_kernel(const unsigned* __restrict__ ebuf, const int* __restrict__ cntg,
                             int* __restrict__ row_ptr, int* __restrict__ col,
                             float* __restrict__ dinv, int N, int E) {
    __shared__ int deg[512];
    __shared__ int sh[256];
    int b = blockIdx.x;
    int tid = threadIdx.x;

    int v = cntg[tid];
    sh[tid] = v;
    __syncthreads();
    int val = v;
    for (int off = 1; off < 256; off <<= 1) {
        int add = 0;
        if (tid >= off) add = sh[tid - off];
        __syncthreads();
        val += add;
        sh[tid] = val;
        __syncthreads();
    }
    int start = (b > 0) ? sh[b - 1] : 0;
    int cnt = cntg[b];
    __syncthreads();

    int nodeBase = b << 9;
    int nn = N - nodeBase;
    if (nn > 512) nn = 512;
    if (nn < 0) nn = 0;
    const unsigned* eb = ebuf + (size_t)b * BCAP;

    deg[tid] = 0;
    deg[tid + 256] = 0;
    __syncthreads();
    for (int j = tid; j < cnt; j += 256) {
        atomicAdd(&deg[eb[j] & 511u], 1);
    }
    __syncthreads();

    int i0 = tid * 2, i1 = i0 + 1;
    int v0 = deg[i0], v1 = deg[i1];
    int tot = v0 + v1;
    sh[tid] = tot;
    __syncthreads();
    int val2 = tot;
    for (int off = 1; off < 256; off <<= 1) {
        int add = 0;
        if (tid >= off) add = sh[tid - off];
        __syncthreads();
        val2 += add;
        sh[tid] = val2;
        __syncthreads();
    }
    int excl = val2 - tot;

    if (i0 < nn) { row_ptr[nodeBase + i0] = start + excl;      dinv[nodeBase + i0] = rsqrtf((float)v0 + 1.0f); }
    if (i1 < nn) { row_ptr[nodeBase + i1] = start + excl + v0; dinv[nodeBase + i1] = rsqrtf((float)v1 + 1.0f); }
    if (b == 0 && tid == 0) row_ptr[N] = E;
    deg[i0] = start + excl;
    deg[i1] = start + excl + v0;
    __syncthreads();

    for (int j = tid; j < cnt; j += 256) {
        unsigned rec = eb[j];
        int pos = atomicAdd(&deg[rec & 511u], 1);
        col[pos] = (int)(rec >> 9);
    }
}

// ---------------- fused convert + weight pack (fp16) ----------------

__global__ void cvtpack_kernel(const float* __restrict__ x, unsigned short* __restrict__ xb,
                               int n4, int npad, const float* __restrict__ dinv,
                               const float* __restrict__ W1, const float* __restrict__ Wh,
                               const float* __restrict__ W2, unsigned short* __restrict__ wp1,
                               unsigned short* __restrict__ wph, unsigned short* __restrict__ wp2) {
    int bid = blockIdx.x;
    if (bid < 16) {
        int i = bid * 256 + threadIdx.x;   // i in [0,4096)
        int j = i & 7;
        int lane = (i >> 3) & 63;
        int hh = (i >> 9) & 1;
        int t = i >> 10;
        int k = hh * 32 + (lane >> 4) * 8 + j;
        int cc = t * 16 + (lane & 15);
        wp1[i] = f16r(W1[k * 64 + cc]);
        wph[i] = f16r(Wh[k * 64 + cc]);
        if (t < 3) wp2[i] = f16r(cc < 40 ? W2[k * 40 + cc] : 0.f);
    } else {
        if (bid == 16 && threadIdx.x < 8) {
            *(uint4*)(xb + (size_t)npad * 64 + threadIdx.x * 8) = make_uint4(0, 0, 0, 0);
        }
        int i = (bid - 16) * 256 + threadIdx.x;
        if (i < n4) {
            float dn = dinv[i >> 4];
            float4 v = *(const float4*)(x + (size_t)i * 4);
            ushort4 o;
            o.x = f16r(v.x * dn); o.y = f16r(v.y * dn);
            o.z = f16r(v.z * dn); o.w = f16r(v.w * dn);
            *(ushort4*)(xb + (size_t)i * 4) = o;
        }
    }
}

// ---------------- fused aggregate + GEMM ----------------
// One block = one 16-node MFMA tile = 4 waves. Each wave aggregates its 4
// nodes (identical inner loop to the standalone agg kernel: one wave per
// node, 8 edge slots x 8 channel-octs, zero-row tail) and writes the
// di-scaled f16 row into a padded LDS tile. After one barrier, each wave
// computes one 16-col t-tile of out = relu(tile @ W + b) * dinv straight
// from LDS -- the aggA HBM round-trip is gone.
// LDS row stride 72 shorts (144 B): 16B-aligned for ds_read_b128 and gives
// a uniform bank spread ((4(c+q))%32 -> exactly 8 lanes per 4-bank window).

__launch_bounds__(256, 8)
__global__ void fused_relu_kernel(const unsigned short* __restrict__ h,
                                  const int* __restrict__ row_ptr,
                                  const int* __restrict__ col,
                                  const float* __restrict__ dinv,
                                  const unsigned short* __restrict__ wp,
                                  const float* __restrict__ bias,
                                  unsigned short* __restrict__ out,
                                  int n, int zrow) {
    __shared__ unsigned short tile[16][72];
    if (blockIdx.x == 0 && threadIdx.x < 8) {
        *(uint4*)(out + (size_t)zrow * 64 + threadIdx.x * 8) = make_uint4(0, 0, 0, 0);
    }
    int tid = threadIdx.x;
    int w = tid >> 6;                    // wave id = t-tile id
    int lane = tid & 63;
    int sub = lane >> 3;                 // edge slot 0..7
    unsigned choff = (lane & 7) * 16u;   // byte offset of channel-oct in 128B row
    int nodeBase = blockIdx.x * 16;

#pragma unroll 1
    for (int i = 0; i < 4; ++i) {
        int row = w * 4 + i;
        int node = nodeBase + row;
        half2v a0 = (half2v)0, a1 = (half2v)0, a2 = (half2v)0, a3 = (half2v)0;
        if (node < n) {
            int beg = row_ptr[node];
            int deg = row_ptr[node + 1] - beg;
            float di = dinv[node];
            int total = deg + 1;         // + self edge
            int base = 0;
            while (base < total) {
                int vi = base + lane;
                int idx = zrow;          // tail -> zero row
                if (vi < deg) idx = col[beg + vi];
                else if (vi == deg) idx = node;
                int cnt = min(total - base, 64);
#pragma unroll
                for (int it = 0; it < 4; ++it) {
                    int c0 = it * 16;
                    if (c0 >= cnt) break;  // wave-uniform
                    int s0 = __shfl(idx, c0 + sub);
                    int s1 = __shfl(idx, c0 + 8 + sub);
                    uint4 u0 = *(const uint4*)((const char*)h + (((unsigned)s0 << 7) + choff));
                    uint4 u1 = *(const uint4*)((const char*)h + (((unsigned)s1 << 7) + choff));
                    a0 += h2(u0.x);  a1 += h2(u0.y);  a2 += h2(u0.z);  a3 += h2(u0.w);
                    a0 += h2(u1.x);  a1 += h2(u1.y);  a2 += h2(u1.z);  a3 += h2(u1.w);
                }
                base += cnt;
            }
#pragma unroll
            for (int off = 8; off <= 32; off <<= 1) {
                a0 += __builtin_bit_cast(half2v, __shfl_xor(__builtin_bit_cast(int, a0), off));
                a1 += __builtin_bit_cast(half2v, __shfl_xor(__builtin_bit_cast(int, a1), off));
                a2 += __builtin_bit_cast(half2v, __shfl_xor(__builtin_bit_cast(int, a2), off));
                a3 += __builtin_bit_cast(half2v, __shfl_xor(__builtin_bit_cast(int, a3), off));
            }
            if (sub == 0) {
                half2v dih = __builtin_bit_cast(half2v, __builtin_amdgcn_cvt_pkrtz(di, di));
                a0 *= dih; a1 *= dih; a2 *= dih; a3 *= dih;
                uint4 o;
                o.x = __builtin_bit_cast(unsigned, a0);
                o.y = __builtin_bit_cast(unsigned, a1);
                o.z = __builtin_bit_cast(unsigned, a2);
                o.w = __builtin_bit_cast(unsigned, a3);
                *(uint4*)((char*)&tile[row][0] + choff) = o;
            }
        } else if (sub == 0) {
            *(uint4*)((char*)&tile[row][0] + choff) = make_uint4(0, 0, 0, 0);
        }
    }
    __syncthreads();

    // GEMM phase: wave w computes output cols [w*16, w*16+16).
    int q = lane >> 4, c = lane & 15;
    half8 bf0 = *(const half8*)(wp + w * 1024 + lane * 8);
    half8 bf1 = *(const half8*)(wp + w * 1024 + 512 + lane * 8);
    float bs = bias[w * 16 + c];
    half8 a0 = *(const half8*)&tile[c][q * 8];
    half8 a1 = *(const half8*)&tile[c][32 + q * 8];
    f32x4 z = {0.f, 0.f, 0.f, 0.f};
    z = __builtin_amdgcn_mfma_f32_16x16x32_f16(a0, bf0, z, 0, 0, 0);
    z = __builtin_amdgcn_mfma_f32_16x16x32_f16(a1, bf1, z, 0, 0, 0);
#pragma unroll
    for (int r = 0; r < 4; ++r) {
        int node = nodeBase + q * 4 + r;
        if (node < n) {
            float dn = dinv[node];
            out[(size_t)node * 64 + w * 16 + c] = f16r(fmaxf(z[r] + bs, 0.f) * dn);
        }
    }
}

// Final layer: same fused agg phase; wave 0 then runs all 3 t-tiles of
// A @ W2 + b2 and the log-softmax epilogue (40 cols).

__launch_bounds__(256, 8)
__global__ void fused_lsm_kernel(const unsigned short* __restrict__ h,
                                 const int* __restrict__ row_ptr,
                                 const int* __restrict__ col,
                                 const float* __restrict__ dinv,
                                 const unsigned short* __restrict__ wp,
                                 const float* __restrict__ bias,
                                 float* __restrict__ out,
                                 int n, int zrow) {
    __shared__ unsigned short tile[16][72];
    int tid = threadIdx.x;
    int w = tid >> 6;
    int lane = tid & 63;
    int sub = lane >> 3;
    unsigned choff = (lane & 7) * 16u;
    int nodeBase = blockIdx.x * 16;

#pragma unroll 1
    for (int i = 0; i < 4; ++i) {
        int row = w * 4 + i;
        int node = nodeBase + row;
        half2v a0 = (half2v)0, a1 = (half2v)0, a2 = (half2v)0, a3 = (half2v)0;
        if (node < n) {
            int beg = row_ptr[node];
            int deg = row_ptr[node + 1] - beg;
            float di = dinv[node];
            int total = deg + 1;
            int base = 0;
            while (base < total) {
                int vi = base + lane;
                int idx = zrow;
                if (vi < deg) idx = col[beg + vi];
                else if (vi == deg) idx = node;
                int cnt = min(total - base, 64);
#pragma unroll
                for (int it = 0; it < 4; ++it) {
                    int c0 = it * 16;
                    if (c0 >= cnt) break;
                    int s0 = __shfl(idx, c0 + sub);
                    int s1 = __shfl(idx, c0 + 8 + sub);
                    uint4 u0 = *(const uint4*)((const char*)h + (((unsigned)s0 << 7) + choff));
                    uint4 u1 = *(const uint4*)((const char*)h + (((unsigned)s1 << 7) + choff));
                    a0 += h2(u0.x);  a1 += h2(u0.y);  a2 += h2(u0.z);  a3 += h2(u0.w);
                    a0 += h2(u1.x);  a1 += h2(u1.y);  a2 += h2(u1.z);  a3 += h2(u1.w);
                }
                base += cnt;
            }
#pragma unroll
            for (int off = 8; off <= 32; off <<= 1) {
                a0 += __builtin_bit_cast(half2v, __shfl_xor(__builtin_bit_cast(int, a0), off));
                a1 += __builtin_bit_cast(half2v, __shfl_xor(__builtin_bit_cast(int, a1), off));
                a2 += __builtin_bit_cast(half2v, __shfl_xor(__builtin_bit_cast(int, a2), off));
                a3 += __builtin_bit_cast(half2v, __shfl_xor(__builtin_bit_cast(int, a3), off));
            }
            if (sub == 0) {
                half2v dih = __builtin_bit_cast(half2v, __builtin_amdgcn_cvt_pkrtz(di, di));
                a0 *= dih; a1 *= dih; a2 *= dih; a3 *= dih;
                uint4 o;
                o.x = __builtin_bit_cast(unsigned, a0);
                o.y = __builtin_bit_cast(unsigned, a1);
                o.z = __builtin_bit_cast(unsigned, a2);
                o.w = __builtin_bit_cast(unsigned, a3);
                *(uint4*)((char*)&tile[row][0] + choff) = o;
            }
        } else if (sub == 0) {
            *(uint4*)((char*)&tile[row][0] + choff) = make_uint4(0, 0, 0, 0);
        }
    }
    __syncthreads();
    if (w != 0) return;

    int q = lane >> 4, c = lane & 15;
    bool v2ok = (c < 8);   // col 32+c < 40

    half8 bfrag[3][2];
#pragma unroll
    for (int t = 0; t < 3; ++t)
#pragma unroll
        for (int hh = 0; hh < 2; ++hh)
            bfrag[t][hh] = *(const half8*)(wp + t * 1024 + hh * 512 + lane * 8);
    float bs[3];
    bs[0] = bias[c];
    bs[1] = bias[16 + c];
    bs[2] = v2ok ? bias[32 + c] : 0.f;

    half8 a0 = *(const half8*)&tile[c][q * 8];
    half8 a1 = *(const half8*)&tile[c][32 + q * 8];

    f32x4 acc[3];
#pragma unroll
    for (int t = 0; t < 3; ++t) {
        f32x4 z = {0.f, 0.f, 0.f, 0.f};
        z = __builtin_amdgcn_mfma_f32_16x16x32_f16(a0, bfrag[t][0], z, 0, 0, 0);
        z = __builtin_amdgcn_mfma_f32_16x16x32_f16(a1, bfrag[t][1], z, 0, 0, 0);
        acc[t] = z;
    }

#pragma unroll
    for (int r = 0; r < 4; ++r) {
        int node = nodeBase + q * 4 + r;
        if (node < n) {
            float v0 = acc[0][r] + bs[0];
            float v1 = acc[1][r] + bs[1];
            float v2 = v2ok ? (acc[2][r] + bs[2]) : -INFINITY;
            float m = fmaxf(fmaxf(v0, v1), v2);
#pragma unroll
            for (int off = 1; off <= 8; off <<= 1) m = fmaxf(m, __shfl_xor(m, off));
            float s = expf(v0 - m) + expf(v1 - m) + (v2ok ? expf(v2 - m) : 0.f);
#pragma unroll
            for (int off = 1; off <= 8; off <<= 1) s += __shfl_xor(s, off);
            float ls = m + logf(s);
            float* orow = out + (size_t)node * 40;
            orow[c] = v0 - ls;
            orow[16 + c] = v1 - ls;
            if (v2ok) orow[32 + c] = v2 - ls;
        }
    }
}

// ---------------- launch ----------------

extern "C" void kernel_launch(void* const* d_in, const int* in_sizes, int n_in,
                              void* d_out, int out_size, void* d_ws, size_t ws_size,
                              hipStream_t stream) {
    const float* x  = (const float*)d_in[0];
    const int* ei   = (const int*)d_in[1];
    const float* W1 = (const float*)d_in[2];
    const float* b1 = (const float*)d_in[3];
    const float* Wh = (const float*)d_in[4];
    const float* bh = (const float*)d_in[5];
    const float* W2 = (const float*)d_in[6];
    const float* b2 = (const float*)d_in[7];
    float* out = (float*)d_out;

    const int N = in_sizes[0] / 64;
    const int E = in_sizes[1] / 2;
    const int nbuk = (N + 511) >> 9;         // 512-node buckets (needs N <= 131072)
    const int nTiles = (N + 15) / 16;
    const int Npad = nTiles * 16;            // zero-row index; buffers have Npad+1 rows

    const int* srcp = ei;
    const int* dstp = ei + E;

    size_t off = 0;
    auto alloc = [&](size_t bytes) {
        size_t o = off;
        off = (off + bytes + 255) & ~(size_t)255;
        return o;
    };
    char* ws = (char*)d_ws;
    int*      cntg    = (int*)(ws + alloc(256 * 4));
    int*      row_ptr = (int*)(ws + alloc((size_t)(N + 1) * 4));
    float*    dinv    = (float*)(ws + alloc((size_t)N * 4));
    int*      col     = (int*)(ws + alloc((size_t)E * 4));
    unsigned* ebuf    = (unsigned*)(ws + alloc((size_t)nbuk * BCAP * 4));
    unsigned short* wp1  = (unsigned short*)(ws + alloc(4096 * 2));
    unsigned short* wph  = (unsigned short*)(ws + alloc(4096 * 2));
    unsigned short* wp2  = (unsigned short*)(ws + alloc(3072 * 2));
    unsigned short* xb   = (unsigned short*)(ws + alloc((size_t)(Npad + 1) * 64 * 2));
    unsigned short* gA   = (unsigned short*)(ws + alloc((size_t)(Npad + 1) * 64 * 2));
    unsigned short* gB   = (unsigned short*)(ws + alloc((size_t)(Npad + 1) * 64 * 2));
    (void)ws_size;

    hipMemsetAsync(cntg, 0, 256 * 4, stream);

    const int ebGrid = (E + 256 * EPT - 1) / (256 * EPT);
    scat1_kernel<<<ebGrid, 256, 0, stream>>>(srcp, dstp, cntg, ebuf, E);
    build_kernel<<<nbuk, 256, 0, stream>>>(ebuf, cntg, row_ptr, col, dinv, N, E);

    const int n4 = N * 16;   // float4 groups (16 per 64-ch row)
    cvtpack_kernel<<<16 + (n4 + 255) / 256, 256, 0, stream>>>(x, xb, n4, Npad, dinv,
                                                              W1, Wh, W2, wp1, wph, wp2);

    // layer 1: xb -> gA     (agg + GEMM fused; aggA round-trip eliminated)
    fused_relu_kernel<<<nTiles, 256, 0, stream>>>(xb, row_ptr, col, dinv, wp1, b1, gA, N, Npad);
    // layer 2: gA -> gB
    fused_relu_kernel<<<nTiles, 256, 0, stream>>>(gA, row_ptr, col, dinv, wph, bh, gB, N, Npad);
    // layer 3: gB -> out (log-softmax, fp32)
    fused_lsm_kernel<<<nTiles, 256, 0, stream>>>(gB, row_ptr, col, dinv, wp2, b2, out, N, Npad);
}

// Round 2
// 229.032 us; speedup vs baseline: 1.1779x; 1.1002x over previous
//
#include <hip/hip_runtime.h>
#include <hip/hip_bf16.h>
#include <math.h>

#define EPT 16      // edges per thread in scatter kernel
#define BCAP 16384  // bucket capacity (avg ~8.2k for uniform random, +90 sigma)

typedef _Float16 half8 __attribute__((ext_vector_type(8)));
typedef _Float16 half2v __attribute__((ext_vector_type(2)));
typedef float f32x4 __attribute__((ext_vector_type(4)));

__device__ __forceinline__ unsigned short f16r(float f) {
    _Float16 h = (_Float16)f;
    return __builtin_bit_cast(unsigned short, h);
}
__device__ __forceinline__ half2v h2(unsigned u) {
    return __builtin_bit_cast(half2v, u);
}

// ---------------- CSR build: single-pass 512-node bucket binning ----------------
// bucket b = dst >> 9; edge record = (src << 9) | (dst & 511)  [needs N <= 131072]

__global__ void scat1_kernel(const int* __restrict__ src, const int* __restrict__ dst,
                             int* __restrict__ cntg, unsigned* __restrict__ ebuf, int E) {
    __shared__ int lh[256];
    __shared__ int lbase[256];
    int tid = threadIdx.x;
    lh[tid] = 0;
    __syncthreads();
    int base = blockIdx.x * (256 * EPT);
    int ds[EPT], ss[EPT];
#pragma unroll
    for (int k = 0; k < EPT; ++k) {
        int e = base + k * 256 + tid;
        ds[k] = (e < E) ? dst[e] : -1;
        ss[k] = (e < E) ? src[e] : 0;
    }
#pragma unroll
    for (int k = 0; k < EPT; ++k) {
        if (ds[k] >= 0) atomicAdd(&lh[ds[k] >> 9], 1);
    }
    __syncthreads();
    if (lh[tid] > 0) lbase[tid] = atomicAdd(&cntg[tid], lh[tid]);
    lh[tid] = 0;
    __syncthreads();
#pragma unroll
    for (int k = 0; k < EPT; ++k) {
        if (ds[k] >= 0) {
            int b = ds[k] >> 9;
            int pos = lbase[b] + atomicAdd(&lh[b], 1);
            ebuf[(size_t)b * BCAP + pos] = ((unsigned)ss[k] << 9) | (unsigned)(ds[k] & 511);
        }
    }
}

__global__ void build_kernel(const unsigned* __restrict__ ebuf, const int* __restrict__ cntg,
                             int* __restrict__ row_ptr, int* __restrict__ col,
                             float* __restrict__ dinv, int N, int E) {
    __shared__ int deg[512];
    __shared__ int sh[256];
    int b = blockIdx.x;
    int tid = threadIdx.x;

    int v = cntg[tid];
    sh[tid] = v;
    __syncthreads();
    int val = v;
    for (int off = 1; off < 256; off <<= 1) {
        int add = 0;
        if (tid >= off) add = sh[tid - off];
        __syncthreads();
        val += add;
        sh[tid] = val;
        __syncthreads();
    }
    int start = (b > 0) ? sh[b - 1] : 0;
    int cnt = cntg[b];
    __syncthreads();

    int nodeBase = b << 9;
    int nn = N - nodeBase;
    if (nn > 512) nn = 512;
    if (nn < 0) nn = 0;
    const unsigned* eb = ebuf + (size_t)b * BCAP;

    deg[tid] = 0;
    deg[tid + 256] = 0;
    __syncthreads();
    for (int j = tid; j < cnt; j += 256) {
        atomicAdd(&deg[eb[j] & 511u], 1);
    }
    __syncthreads();

    int i0 = tid * 2, i1 = i0 + 1;
    int v0 = deg[i0], v1 = deg[i1];
    int tot = v0 + v1;
    sh[tid] = tot;
    __syncthreads();
    int val2 = tot;
    for (int off = 1; off < 256; off <<= 1) {
        int add = 0;
        if (tid >= off) add = sh[tid - off];
        __syncthreads();
        val2 += add;
        sh[tid] = val2;
        __syncthreads();
    }
    int excl = val2 - tot;

    if (i0 < nn) { row_ptr[nodeBase + i0] = start + excl;      dinv[nodeBase + i0] = rsqrtf((float)v0 + 1.0f); }
    if (i1 < nn) { row_ptr[nodeBase + i1] = start + excl + v0; dinv[nodeBase + i1] = rsqrtf((float)v1 + 1.0f); }
    if (b == 0 && tid == 0) row_ptr[N] = E;
    deg[i0] = start + excl;
    deg[i1] = start + excl + v0;
    __syncthreads();

    for (int j = tid; j < cnt; j += 256) {
        unsigned rec = eb[j];
        int pos = atomicAdd(&deg[rec & 511u], 1);
        col[pos] = (int)(rec >> 9);
    }
}

// ---------------- fused convert + weight pack (fp16) ----------------

__global__ void cvtpack_kernel(const float* __restrict__ x, unsigned short* __restrict__ xb,
                               int n4, int npad, const float* __restrict__ dinv,
                               const float* __restrict__ W1, const float* __restrict__ Wh,
                               const float* __restrict__ W2, unsigned short* __restrict__ wp1,
                               unsigned short* __restrict__ wph, unsigned short* __restrict__ wp2) {
    int bid = blockIdx.x;
    if (bid < 16) {
        int i = bid * 256 + threadIdx.x;   // i in [0,4096)
        int j = i & 7;
        int lane = (i >> 3) & 63;
        int hh = (i >> 9) & 1;
        int t = i >> 10;
        int k = hh * 32 + (lane >> 4) * 8 + j;
        int cc = t * 16 + (lane & 15);
        wp1[i] = f16r(W1[k * 64 + cc]);
        wph[i] = f16r(Wh[k * 64 + cc]);
        if (t < 3) wp2[i] = f16r(cc < 40 ? W2[k * 40 + cc] : 0.f);
    } else {
        if (bid == 16 && threadIdx.x < 8) {
            *(uint4*)(xb + (size_t)npad * 64 + threadIdx.x * 8) = make_uint4(0, 0, 0, 0);
        }
        int i = (bid - 16) * 256 + threadIdx.x;
        if (i < n4) {
            float dn = dinv[i >> 4];
            float4 v = *(const float4*)(x + (size_t)i * 4);
            ushort4 o;
            o.x = f16r(v.x * dn); o.y = f16r(v.y * dn);
            o.z = f16r(v.z * dn); o.w = f16r(v.w * dn);
            *(ushort4*)(xb + (size_t)i * 4) = o;
        }
    }
}

// ---------------- fused aggregate + GEMM ----------------
// One block = one 16-node MFMA tile = 4 waves. Each wave aggregates its 4
// nodes IN PARALLEL: 16 lanes per node (4 node-groups x 2 edge-slots x 8
// channel-octs). Per-lane load counts are identical to the serial-node
// scheme, but the 4 gather chains overlap (wave time ~ max deg, not sum),
// the cross-lane reduce is 2-way instead of 8-way, and all 4 nodes' CSR
// loads issue together. Dual even/odd accumulators keep the f16 sequential
// add-chain depth comparable to the old scheme (rounding parity).
// LDS row stride 72 shorts (144 B): 16B-aligned, uniform bank spread.

__launch_bounds__(256, 8)
__global__ void fused_relu_kernel(const unsigned short* __restrict__ h,
                                  const int* __restrict__ row_ptr,
                                  const int* __restrict__ col,
                                  const float* __restrict__ dinv,
                                  const unsigned short* __restrict__ wp,
                                  const float* __restrict__ bias,
                                  unsigned short* __restrict__ out,
                                  int n, int zrow) {
    __shared__ unsigned short tile[16][72];
    if (blockIdx.x == 0 && threadIdx.x < 8) {
        *(uint4*)(out + (size_t)zrow * 64 + threadIdx.x * 8) = make_uint4(0, 0, 0, 0);
    }
    int tid = threadIdx.x;
    int w = tid >> 6;                    // wave id = t-tile id
    int lane = tid & 63;
    int g = lane >> 4;                   // node group 0..3
    int li = lane & 15;
    int sub = li >> 3;                   // edge slot 0/1
    unsigned choff = (li & 7) * 16u;     // byte offset of channel-oct in 128B row
    int nodeBase = blockIdx.x * 16;
    int row = w * 4 + g;
    int node = nodeBase + row;

    int beg = 0, deg = -1;
    float di = 0.f;
    if (node < n) {
        beg = row_ptr[node];
        deg = row_ptr[node + 1] - beg;
        di = dinv[node];
    }
    int total = deg + 1;                 // + self edge (0 for invalid node)
    int nb = (total + 15) >> 4;          // 16-edge batches for this node
    nb = max(nb, __shfl_xor(nb, 16));    // wave-uniform max over the 4 groups
    nb = max(nb, __shfl_xor(nb, 32));

    half2v a0 = (half2v)0, a1 = (half2v)0, a2 = (half2v)0, a3 = (half2v)0;
    half2v c0 = (half2v)0, c1 = (half2v)0, c2 = (half2v)0, c3 = (half2v)0;

    for (int b = 0; b < nb; ++b) {
        int e0 = (b << 4) + li;
        int idx = zrow;                  // pad -> zero row (L1-hot)
        if (e0 < deg) idx = col[beg + e0];
        else if (e0 == deg) idx = node;  // self edge (h'[node] = dn*h[node])
#pragma unroll
        for (int it = 0; it < 8; ++it) {
            int s = __shfl(idx, (g << 4) + it * 2 + sub);
            uint4 u = *(const uint4*)((const char*)h + (((unsigned)s << 7) + choff));
            if (it & 1) { c0 += h2(u.x); c1 += h2(u.y); c2 += h2(u.z); c3 += h2(u.w); }
            else        { a0 += h2(u.x); a1 += h2(u.y); a2 += h2(u.z); a3 += h2(u.w); }
        }
    }
    a0 += c0; a1 += c1; a2 += c2; a3 += c3;
    // reduce the 2 edge slots (lane bit 3)
    a0 += __builtin_bit_cast(half2v, __shfl_xor(__builtin_bit_cast(int, a0), 8));
    a1 += __builtin_bit_cast(half2v, __shfl_xor(__builtin_bit_cast(int, a1), 8));
    a2 += __builtin_bit_cast(half2v, __shfl_xor(__builtin_bit_cast(int, a2), 8));
    a3 += __builtin_bit_cast(half2v, __shfl_xor(__builtin_bit_cast(int, a3), 8));

    if (sub == 0) {
        half2v dih = __builtin_bit_cast(half2v, __builtin_amdgcn_cvt_pkrtz(di, di));
        a0 *= dih; a1 *= dih; a2 *= dih; a3 *= dih;   // v_pk_mul_f16
        uint4 o;
        o.x = __builtin_bit_cast(unsigned, a0);
        o.y = __builtin_bit_cast(unsigned, a1);
        o.z = __builtin_bit_cast(unsigned, a2);
        o.w = __builtin_bit_cast(unsigned, a3);
        *(uint4*)((char*)&tile[row][0] + choff) = o;
    }
    __syncthreads();

    // GEMM phase: wave w computes output cols [w*16, w*16+16).
    int q = lane >> 4, c = lane & 15;
    half8 bf0 = *(const half8*)(wp + w * 1024 + lane * 8);
    half8 bf1 = *(const half8*)(wp + w * 1024 + 512 + lane * 8);
    float bs = bias[w * 16 + c];
    half8 fa0 = *(const half8*)&tile[c][q * 8];
    half8 fa1 = *(const half8*)&tile[c][32 + q * 8];
    f32x4 z = {0.f, 0.f, 0.f, 0.f};
    z = __builtin_amdgcn_mfma_f32_16x16x32_f16(fa0, bf0, z, 0, 0, 0);
    z = __builtin_amdgcn_mfma_f32_16x16x32_f16(fa1, bf1, z, 0, 0, 0);
#pragma unroll
    for (int r = 0; r < 4; ++r) {
        int nodeW = nodeBase + q * 4 + r;
        if (nodeW < n) {
            float dn = dinv[nodeW];
            out[(size_t)nodeW * 64 + w * 16 + c] = f16r(fmaxf(z[r] + bs, 0.f) * dn);
        }
    }
}

// Final layer: same fused agg phase; wave 0 then runs all 3 t-tiles of
// A @ W2 + b2 and the log-softmax epilogue (40 cols).

__launch_bounds__(256, 8)
__global__ void fused_lsm_kernel(const unsigned short* __restrict__ h,
                                 const int* __restrict__ row_ptr,
                                 const int* __restrict__ col,
                                 const float* __restrict__ dinv,
                                 const unsigned short* __restrict__ wp,
                                 const float* __restrict__ bias,
                                 float* __restrict__ out,
                                 int n, int zrow) {
    __shared__ unsigned short tile[16][72];
    int tid = threadIdx.x;
    int w = tid >> 6;
    int lane = tid & 63;
    int g = lane >> 4;
    int li = lane & 15;
    int sub = li >> 3;
    unsigned choff = (li & 7) * 16u;
    int nodeBase = blockIdx.x * 16;
    int row = w * 4 + g;
    int node = nodeBase + row;

    int beg = 0, deg = -1;
    float di = 0.f;
    if (node < n) {
        beg = row_ptr[node];
        deg = row_ptr[node + 1] - beg;
        di = dinv[node];
    }
    int total = deg + 1;
    int nb = (total + 15) >> 4;
    nb = max(nb, __shfl_xor(nb, 16));
    nb = max(nb, __shfl_xor(nb, 32));

    half2v a0 = (half2v)0, a1 = (half2v)0, a2 = (half2v)0, a3 = (half2v)0;
    half2v c0a = (half2v)0, c1a = (half2v)0, c2a = (half2v)0, c3a = (half2v)0;

    for (int b = 0; b < nb; ++b) {
        int e0 = (b << 4) + li;
        int idx = zrow;
        if (e0 < deg) idx = col[beg + e0];
        else if (e0 == deg) idx = node;
#pragma unroll
        for (int it = 0; it < 8; ++it) {
            int s = __shfl(idx, (g << 4) + it * 2 + sub);
            uint4 u = *(const uint4*)((const char*)h + (((unsigned)s << 7) + choff));
            if (it & 1) { c0a += h2(u.x); c1a += h2(u.y); c2a += h2(u.z); c3a += h2(u.w); }
            else        { a0 += h2(u.x);  a1 += h2(u.y);  a2 += h2(u.z);  a3 += h2(u.w); }
        }
    }
    a0 += c0a; a1 += c1a; a2 += c2a; a3 += c3a;
    a0 += __builtin_bit_cast(half2v, __shfl_xor(__builtin_bit_cast(int, a0), 8));
    a1 += __builtin_bit_cast(half2v, __shfl_xor(__builtin_bit_cast(int, a1), 8));
    a2 += __builtin_bit_cast(half2v, __shfl_xor(__builtin_bit_cast(int, a2), 8));
    a3 += __builtin_bit_cast(half2v, __shfl_xor(__builtin_bit_cast(int, a3), 8));

    if (sub == 0) {
        half2v dih = __builtin_bit_cast(half2v, __builtin_amdgcn_cvt_pkrtz(di, di));
        a0 *= dih; a1 *= dih; a2 *= dih; a3 *= dih;
        uint4 o;
        o.x = __builtin_bit_cast(unsigned, a0);
        o.y = __builtin_bit_cast(unsigned, a1);
        o.z = __builtin_bit_cast(unsigned, a2);
        o.w = __builtin_bit_cast(unsigned, a3);
        *(uint4*)((char*)&tile[row][0] + choff) = o;
    }
    __syncthreads();
    if (w != 0) return;

    int q = lane >> 4, c = lane & 15;
    bool v2ok = (c < 8);   // col 32+c < 40

    half8 bfrag[3][2];
#pragma unroll
    for (int t = 0; t < 3; ++t)
#pragma unroll
        for (int hh = 0; hh < 2; ++hh)
            bfrag[t][hh] = *(const half8*)(wp + t * 1024 + hh * 512 + lane * 8);
    float bs[3];
    bs[0] = bias[c];
    bs[1] = bias[16 + c];
    bs[2] = v2ok ? bias[32 + c] : 0.f;

    half8 fa0 = *(const half8*)&tile[c][q * 8];
    half8 fa1 = *(const half8*)&tile[c][32 + q * 8];

    f32x4 acc[3];
#pragma unroll
    for (int t = 0; t < 3; ++t) {
        f32x4 z = {0.f, 0.f, 0.f, 0.f};
        z = __builtin_amdgcn_mfma_f32_16x16x32_f16(fa0, bfrag[t][0], z, 0, 0, 0);
        z = __builtin_amdgcn_mfma_f32_16x16x32_f16(fa1, bfrag[t][1], z, 0, 0, 0);
        acc[t] = z;
    }

#pragma unroll
    for (int r = 0; r < 4; ++r) {
        int nodeW = nodeBase + q * 4 + r;
        if (nodeW < n) {
            float v0 = acc[0][r] + bs[0];
            float v1 = acc[1][r] + bs[1];
            float v2 = v2ok ? (acc[2][r] + bs[2]) : -INFINITY;
            float m = fmaxf(fmaxf(v0, v1), v2);
#pragma unroll
            for (int off = 1; off <= 8; off <<= 1) m = fmaxf(m, __shfl_xor(m, off));
            float s = expf(v0 - m) + expf(v1 - m) + (v2ok ? expf(v2 - m) : 0.f);
#pragma unroll
            for (int off = 1; off <= 8; off <<= 1) s += __shfl_xor(s, off);
            float ls = m + logf(s);
            float* orow = out + (size_t)nodeW * 40;
            orow[c] = v0 - ls;
            orow[16 + c] = v1 - ls;
            if (v2ok) orow[32 + c] = v2 - ls;
        }
    }
}

// ---------------- launch ----------------

extern "C" void kernel_launch(void* const* d_in, const int* in_sizes, int n_in,
                              void* d_out, int out_size, void* d_ws, size_t ws_size,
                              hipStream_t stream) {
    const float* x  = (const float*)d_in[0];
    const int* ei   = (const int*)d_in[1];
    const float* W1 = (const float*)d_in[2];
    const float* b1 = (const float*)d_in[3];
    const float* Wh = (const float*)d_in[4];
    const float* bh = (const float*)d_in[5];
    const float* W2 = (const float*)d_in[6];
    const float* b2 = (const float*)d_in[7];
    float* out = (float*)d_out;

    const int N = in_sizes[0] / 64;
    const int E = in_sizes[1] / 2;
    const int nbuk = (N + 511) >> 9;         // 512-node buckets (needs N <= 131072)
    const int nTiles = (N + 15) / 16;
    const int Npad = nTiles * 16;            // zero-row index; buffers have Npad+1 rows

    const int* srcp = ei;
    const int* dstp = ei + E;

    size_t off = 0;
    auto alloc = [&](size_t bytes) {
        size_t o = off;
        off = (off + bytes + 255) & ~(size_t)255;
        return o;
    };
    char* ws = (char*)d_ws;
    int*      cntg    = (int*)(ws + alloc(256 * 4));
    int*      row_ptr = (int*)(ws + alloc((size_t)(N + 1) * 4));
    float*    dinv    = (float*)(ws + alloc((size_t)N * 4));
    int*      col     = (int*)(ws + alloc((size_t)E * 4));
    unsigned* ebuf    = (unsigned*)(ws + alloc((size_t)nbuk * BCAP * 4));
    unsigned short* wp1  = (unsigned short*)(ws + alloc(4096 * 2));
    unsigned short* wph  = (unsigned short*)(ws + alloc(4096 * 2));
    unsigned short* wp2  = (unsigned short*)(ws + alloc(3072 * 2));
    unsigned short* xb   = (unsigned short*)(ws + alloc((size_t)(Npad + 1) * 64 * 2));
    unsigned short* gA   = (unsigned short*)(ws + alloc((size_t)(Npad + 1) * 64 * 2));
    unsigned short* gB   = (unsigned short*)(ws + alloc((size_t)(Npad + 1) * 64 * 2));
    (void)ws_size;

    hipMemsetAsync(cntg, 0, 256 * 4, stream);

    const int ebGrid = (E + 256 * EPT - 1) / (256 * EPT);
    scat1_kernel<<<ebGrid, 256, 0, stream>>>(srcp, dstp, cntg, ebuf, E);
    build_kernel<<<nbuk, 256, 0, stream>>>(ebuf, cntg, row_ptr, col, dinv, N, E);

    const int n4 = N * 16;   // float4 groups (16 per 64-ch row)
    cvtpack_kernel<<<16 + (n4 + 255) / 256, 256, 0, stream>>>(x, xb, n4, Npad, dinv,
                                                              W1, Wh, W2, wp1, wph, wp2);

    // layer 1: xb -> gA     (agg + GEMM fused)
    fused_relu_kernel<<<nTiles, 256, 0, stream>>>(xb, row_ptr, col, dinv, wp1, b1, gA, N, Npad);
    // layer 2: gA -> gB
    fused_relu_kernel<<<nTiles, 256, 0, stream>>>(gA, row_ptr, col, dinv, wph, bh, gB, N, Npad);
    // layer 3: gB -> out (log-softmax, fp32)
    fused_lsm_kernel<<<nTiles, 256, 0, stream>>>(gB, row_ptr, col, dinv, wp2, b2, out, N, Npad);
}

// Round 3
// 226.552 us; speedup vs baseline: 1.1908x; 1.0109x over previous
//
#include <hip/hip_runtime.h>
#include <hip/hip_bf16.h>
#include <math.h>

#define EPT 16      // edges per thread in scatter kernel
#define BCAP 16384  // bucket capacity (avg ~8.2k for uniform random, +90 sigma)

typedef _Float16 half8 __attribute__((ext_vector_type(8)));
typedef _Float16 half2v __attribute__((ext_vector_type(2)));
typedef float f32x4 __attribute__((ext_vector_type(4)));

__device__ __forceinline__ unsigned short f16r(float f) {
    _Float16 h = (_Float16)f;
    return __builtin_bit_cast(unsigned short, h);
}
__device__ __forceinline__ half2v h2(unsigned u) {
    return __builtin_bit_cast(half2v, u);
}

// ---------------- CSR build: single-pass 512-node bucket binning ----------------
// bucket b = dst >> 9; edge record = (src << 9) | (dst & 511)  [needs N <= 131072]

__global__ void scat1_kernel(const int* __restrict__ src, const int* __restrict__ dst,
                             int* __restrict__ cntg, unsigned* __restrict__ ebuf, int E) {
    __shared__ int lh[256];
    __shared__ int lbase[256];
    int tid = threadIdx.x;
    lh[tid] = 0;
    __syncthreads();
    int base = blockIdx.x * (256 * EPT);
    int ds[EPT], ss[EPT];
#pragma unroll
    for (int k = 0; k < EPT; ++k) {
        int e = base + k * 256 + tid;
        ds[k] = (e < E) ? dst[e] : -1;
        ss[k] = (e < E) ? src[e] : 0;
    }
#pragma unroll
    for (int k = 0; k < EPT; ++k) {
        if (ds[k] >= 0) atomicAdd(&lh[ds[k] >> 9], 1);
    }
    __syncthreads();
    if (lh[tid] > 0) lbase[tid] = atomicAdd(&cntg[tid], lh[tid]);
    lh[tid] = 0;
    __syncthreads();
#pragma unroll
    for (int k = 0; k < EPT; ++k) {
        if (ds[k] >= 0) {
            int b = ds[k] >> 9;
            int pos = lbase[b] + atomicAdd(&lh[b], 1);
            ebuf[(size_t)b * BCAP + pos] = ((unsigned)ss[k] << 9) | (unsigned)(ds[k] & 511);
        }
    }
}

__global__ void build_kernel(const unsigned* __restrict__ ebuf, const int* __restrict__ cntg,
                             int* __restrict__ row_ptr, int* __restrict__ col,
                             float* __restrict__ dinv, int N, int E) {
    __shared__ int deg[512];
    __shared__ int sh[256];
    int b = blockIdx.x;
    int tid = threadIdx.x;

    int v = cntg[tid];
    sh[tid] = v;
    __syncthreads();
    int val = v;
    for (int off = 1; off < 256; off <<= 1) {
        int add = 0;
        if (tid >= off) add = sh[tid - off];
        __syncthreads();
        val += add;
        sh[tid] = val;
        __syncthreads();
    }
    int start = (b > 0) ? sh[b - 1] : 0;
    int cnt = cntg[b];
    __syncthreads();

    int nodeBase = b << 9;
    int nn = N - nodeBase;
    if (nn > 512) nn = 512;
    if (nn < 0) nn = 0;
    const unsigned* eb = ebuf + (size_t)b * BCAP;

    deg[tid] = 0;
    deg[tid + 256] = 0;
    __syncthreads();
    for (int j = tid; j < cnt; j += 256) {
        atomicAdd(&deg[eb[j] & 511u], 1);
    }
    __syncthreads();

    int i0 = tid * 2, i1 = i0 + 1;
    int v0 = deg[i0], v1 = deg[i1];
    int tot = v0 + v1;
    sh[tid] = tot;
    __syncthreads();
    int val2 = tot;
    for (int off = 1; off < 256; off <<= 1) {
        int add = 0;
        if (tid >= off) add = sh[tid - off];
        __syncthreads();
        val2 += add;
        sh[tid] = val2;
        __syncthreads();
    }
    int excl = val2 - tot;

    if (i0 < nn) { row_ptr[nodeBase + i0] = start + excl;      dinv[nodeBase + i0] = rsqrtf((float)v0 + 1.0f); }
    if (i1 < nn) { row_ptr[nodeBase + i1] = start + excl + v0; dinv[nodeBase + i1] = rsqrtf((float)v1 + 1.0f); }
    if (b == 0 && tid == 0) row_ptr[N] = E;
    deg[i0] = start + excl;
    deg[i1] = start + excl + v0;
    __syncthreads();

    for (int j = tid; j < cnt; j += 256) {
        unsigned rec = eb[j];
        int pos = atomicAdd(&deg[rec & 511u], 1);
        col[pos] = (int)(rec >> 9);
    }
}

// ---------------- fused convert + weight pack (fp16) ----------------

__global__ void cvtpack_kernel(const float* __restrict__ x, unsigned short* __restrict__ xb,
                               int n4, int npad, const float* __restrict__ dinv,
                               const float* __restrict__ W1, const float* __restrict__ Wh,
                               const float* __restrict__ W2, unsigned short* __restrict__ wp1,
                               unsigned short* __restrict__ wph, unsigned short* __restrict__ wp2) {
    int bid = blockIdx.x;
    if (bid < 16) {
        int i = bid * 256 + threadIdx.x;   // i in [0,4096)
        int j = i & 7;
        int lane = (i >> 3) & 63;
        int hh = (i >> 9) & 1;
        int t = i >> 10;
        int k = hh * 32 + (lane >> 4) * 8 + j;
        int cc = t * 16 + (lane & 15);
        wp1[i] = f16r(W1[k * 64 + cc]);
        wph[i] = f16r(Wh[k * 64 + cc]);
        if (t < 3) wp2[i] = f16r(cc < 40 ? W2[k * 40 + cc] : 0.f);
    } else {
        if (bid == 16 && threadIdx.x < 8) {
            *(uint4*)(xb + (size_t)npad * 64 + threadIdx.x * 8) = make_uint4(0, 0, 0, 0);
        }
        int i = (bid - 16) * 256 + threadIdx.x;
        if (i < n4) {
            float dn = dinv[i >> 4];
            float4 v = *(const float4*)(x + (size_t)i * 4);
            ushort4 o;
            o.x = f16r(v.x * dn); o.y = f16r(v.y * dn);
            o.z = f16r(v.z * dn); o.w = f16r(v.w * dn);
            *(ushort4*)(xb + (size_t)i * 4) = o;
        }
    }
}

// ---------------- fused aggregate + GEMM ----------------
// One block = one 16-node MFMA tile = 4 waves, 16 lanes per node
// (4 node-groups x 2 edge-slots x 8 channel-octs).
// MLP restructure: per 16-edge batch, all 8 gather loads are issued into a
// statically-indexed register array BEFORE any accumulate (sched_barrier(0)
// pins the boundary), and the next batch's col/idx load is issued ahead of
// the gather cluster. This keeps ~9 loads in flight per wave instead of the
// 1-2 the compiler chose at VGPR_Count=20 (the round-1 latency signature).
// Accumulation order per batch is unchanged (even/odd split) -> same absmax.
// LDS row stride 72 shorts (144 B): 16B-aligned, uniform bank spread.

__launch_bounds__(256, 8)
__global__ void fused_relu_kernel(const unsigned short* __restrict__ h,
                                  const int* __restrict__ row_ptr,
                                  const int* __restrict__ col,
                                  const float* __restrict__ dinv,
                                  const unsigned short* __restrict__ wp,
                                  const float* __restrict__ bias,
                                  unsigned short* __restrict__ out,
                                  int n, int zrow) {
    __shared__ unsigned short tile[16][72];
    if (blockIdx.x == 0 && threadIdx.x < 8) {
        *(uint4*)(out + (size_t)zrow * 64 + threadIdx.x * 8) = make_uint4(0, 0, 0, 0);
    }
    int tid = threadIdx.x;
    int w = tid >> 6;                    // wave id = t-tile id
    int lane = tid & 63;
    int g = lane >> 4;                   // node group 0..3
    int li = lane & 15;
    int sub = li >> 3;                   // edge slot 0/1
    unsigned choff = (li & 7) * 16u;     // byte offset of channel-oct in 128B row
    int nodeBase = blockIdx.x * 16;
    int row = w * 4 + g;
    int node = nodeBase + row;

    int beg = 0, deg = -1;
    float di = 0.f;
    if (node < n) {
        beg = row_ptr[node];
        deg = row_ptr[node + 1] - beg;
        di = dinv[node];
    }
    int total = deg + 1;                 // + self edge (0 for invalid node)
    int nb = (total + 15) >> 4;          // 16-edge batches for this node
    nb = max(nb, __shfl_xor(nb, 16));    // wave-uniform max over the 4 groups
    nb = max(nb, __shfl_xor(nb, 32));

    half2v a0 = (half2v)0, a1 = (half2v)0, a2 = (half2v)0, a3 = (half2v)0;
    half2v c0 = (half2v)0, c1 = (half2v)0, c2 = (half2v)0, c3 = (half2v)0;

    // batch-0 idx
    int idx;
    {
        int e0 = li;
        idx = zrow;
        if (e0 < deg) idx = col[beg + e0];
        else if (e0 == deg) idx = node;
    }
    for (int b = 0; b < nb; ++b) {
        // prefetch next batch's idx under this batch's gathers
        int nidx = zrow;
        if (b + 1 < nb) {
            int e0 = ((b + 1) << 4) + li;
            if (e0 < deg) nidx = col[beg + e0];
            else if (e0 == deg) nidx = node;
        }
        uint4 u[8];
#pragma unroll
        for (int it = 0; it < 8; ++it) {
            int s = __shfl(idx, (g << 4) + it * 2 + sub);
            u[it] = *(const uint4*)((const char*)h + (((unsigned)s << 7) + choff));
        }
        __builtin_amdgcn_sched_barrier(0);   // all 8 gathers issued before consumes
#pragma unroll
        for (int it = 0; it < 8; ++it) {
            if (it & 1) { c0 += h2(u[it].x); c1 += h2(u[it].y); c2 += h2(u[it].z); c3 += h2(u[it].w); }
            else        { a0 += h2(u[it].x); a1 += h2(u[it].y); a2 += h2(u[it].z); a3 += h2(u[it].w); }
        }
        idx = nidx;
    }
    a0 += c0; a1 += c1; a2 += c2; a3 += c3;
    // reduce the 2 edge slots (lane bit 3)
    a0 += __builtin_bit_cast(half2v, __shfl_xor(__builtin_bit_cast(int, a0), 8));
    a1 += __builtin_bit_cast(half2v, __shfl_xor(__builtin_bit_cast(int, a1), 8));
    a2 += __builtin_bit_cast(half2v, __shfl_xor(__builtin_bit_cast(int, a2), 8));
    a3 += __builtin_bit_cast(half2v, __shfl_xor(__builtin_bit_cast(int, a3), 8));

    if (sub == 0) {
        half2v dih = __builtin_bit_cast(half2v, __builtin_amdgcn_cvt_pkrtz(di, di));
        a0 *= dih; a1 *= dih; a2 *= dih; a3 *= dih;   // v_pk_mul_f16
        uint4 o;
        o.x = __builtin_bit_cast(unsigned, a0);
        o.y = __builtin_bit_cast(unsigned, a1);
        o.z = __builtin_bit_cast(unsigned, a2);
        o.w = __builtin_bit_cast(unsigned, a3);
        *(uint4*)((char*)&tile[row][0] + choff) = o;
    }
    __syncthreads();

    // GEMM phase: wave w computes output cols [w*16, w*16+16).
    int q = lane >> 4, c = lane & 15;
    half8 bf0 = *(const half8*)(wp + w * 1024 + lane * 8);
    half8 bf1 = *(const half8*)(wp + w * 1024 + 512 + lane * 8);
    float bs = bias[w * 16 + c];
    half8 fa0 = *(const half8*)&tile[c][q * 8];
    half8 fa1 = *(const half8*)&tile[c][32 + q * 8];
    f32x4 z = {0.f, 0.f, 0.f, 0.f};
    z = __builtin_amdgcn_mfma_f32_16x16x32_f16(fa0, bf0, z, 0, 0, 0);
    z = __builtin_amdgcn_mfma_f32_16x16x32_f16(fa1, bf1, z, 0, 0, 0);
#pragma unroll
    for (int r = 0; r < 4; ++r) {
        int nodeW = nodeBase + q * 4 + r;
        if (nodeW < n) {
            float dn = dinv[nodeW];
            out[(size_t)nodeW * 64 + w * 16 + c] = f16r(fmaxf(z[r] + bs, 0.f) * dn);
        }
    }
}

// Final layer: same fused agg phase; wave 0 then runs all 3 t-tiles of
// A @ W2 + b2 and the log-softmax epilogue (40 cols).

__launch_bounds__(256, 8)
__global__ void fused_lsm_kernel(const unsigned short* __restrict__ h,
                                 const int* __restrict__ row_ptr,
                                 const int* __restrict__ col,
                                 const float* __restrict__ dinv,
                                 const unsigned short* __restrict__ wp,
                                 const float* __restrict__ bias,
                                 float* __restrict__ out,
                                 int n, int zrow) {
    __shared__ unsigned short tile[16][72];
    int tid = threadIdx.x;
    int w = tid >> 6;
    int lane = tid & 63;
    int g = lane >> 4;
    int li = lane & 15;
    int sub = li >> 3;
    unsigned choff = (li & 7) * 16u;
    int nodeBase = blockIdx.x * 16;
    int row = w * 4 + g;
    int node = nodeBase + row;

    int beg = 0, deg = -1;
    float di = 0.f;
    if (node < n) {
        beg = row_ptr[node];
        deg = row_ptr[node + 1] - beg;
        di = dinv[node];
    }
    int total = deg + 1;
    int nb = (total + 15) >> 4;
    nb = max(nb, __shfl_xor(nb, 16));
    nb = max(nb, __shfl_xor(nb, 32));

    half2v a0 = (half2v)0, a1 = (half2v)0, a2 = (half2v)0, a3 = (half2v)0;
    half2v c0a = (half2v)0, c1a = (half2v)0, c2a = (half2v)0, c3a = (half2v)0;

    int idx;
    {
        int e0 = li;
        idx = zrow;
        if (e0 < deg) idx = col[beg + e0];
        else if (e0 == deg) idx = node;
    }
    for (int b = 0; b < nb; ++b) {
        int nidx = zrow;
        if (b + 1 < nb) {
            int e0 = ((b + 1) << 4) + li;
            if (e0 < deg) nidx = col[beg + e0];
            else if (e0 == deg) nidx = node;
        }
        uint4 u[8];
#pragma unroll
        for (int it = 0; it < 8; ++it) {
            int s = __shfl(idx, (g << 4) + it * 2 + sub);
            u[it] = *(const uint4*)((const char*)h + (((unsigned)s << 7) + choff));
        }
        __builtin_amdgcn_sched_barrier(0);
#pragma unroll
        for (int it = 0; it < 8; ++it) {
            if (it & 1) { c0a += h2(u[it].x); c1a += h2(u[it].y); c2a += h2(u[it].z); c3a += h2(u[it].w); }
            else        { a0 += h2(u[it].x);  a1 += h2(u[it].y);  a2 += h2(u[it].z);  a3 += h2(u[it].w); }
        }
        idx = nidx;
    }
    a0 += c0a; a1 += c1a; a2 += c2a; a3 += c3a;
    a0 += __builtin_bit_cast(half2v, __shfl_xor(__builtin_bit_cast(int, a0), 8));
    a1 += __builtin_bit_cast(half2v, __shfl_xor(__builtin_bit_cast(int, a1), 8));
    a2 += __builtin_bit_cast(half2v, __shfl_xor(__builtin_bit_cast(int, a2), 8));
    a3 += __builtin_bit_cast(half2v, __shfl_xor(__builtin_bit_cast(int, a3), 8));

    if (sub == 0) {
        half2v dih = __builtin_bit_cast(half2v, __builtin_amdgcn_cvt_pkrtz(di, di));
        a0 *= dih; a1 *= dih; a2 *= dih; a3 *= dih;
        uint4 o;
        o.x = __builtin_bit_cast(unsigned, a0);
        o.y = __builtin_bit_cast(unsigned, a1);
        o.z = __builtin_bit_cast(unsigned, a2);
        o.w = __builtin_bit_cast(unsigned, a3);
        *(uint4*)((char*)&tile[row][0] + choff) = o;
    }
    __syncthreads();
    if (w != 0) return;

    int q = lane >> 4, c = lane & 15;
    bool v2ok = (c < 8);   // col 32+c < 40

    half8 bfrag[3][2];
#pragma unroll
    for (int t = 0; t < 3; ++t)
#pragma unroll
        for (int hh = 0; hh < 2; ++hh)
            bfrag[t][hh] = *(const half8*)(wp + t * 1024 + hh * 512 + lane * 8);
    float bs[3];
    bs[0] = bias[c];
    bs[1] = bias[16 + c];
    bs[2] = v2ok ? bias[32 + c] : 0.f;

    half8 fa0 = *(const half8*)&tile[c][q * 8];
    half8 fa1 = *(const half8*)&tile[c][32 + q * 8];

    f32x4 acc[3];
#pragma unroll
    for (int t = 0; t < 3; ++t) {
        f32x4 z = {0.f, 0.f, 0.f, 0.f};
        z = __builtin_amdgcn_mfma_f32_16x16x32_f16(fa0, bfrag[t][0], z, 0, 0, 0);
        z = __builtin_amdgcn_mfma_f32_16x16x32_f16(fa1, bfrag[t][1], z, 0, 0, 0);
        acc[t] = z;
    }

#pragma unroll
    for (int r = 0; r < 4; ++r) {
        int nodeW = nodeBase + q * 4 + r;
        if (nodeW < n) {
            float v0 = acc[0][r] + bs[0];
            float v1 = acc[1][r] + bs[1];
            float v2 = v2ok ? (acc[2][r] + bs[2]) : -INFINITY;
            float m = fmaxf(fmaxf(v0, v1), v2);
#pragma unroll
            for (int off = 1; off <= 8; off <<= 1) m = fmaxf(m, __shfl_xor(m, off));
            float s = expf(v0 - m) + expf(v1 - m) + (v2ok ? expf(v2 - m) : 0.f);
#pragma unroll
            for (int off = 1; off <= 8; off <<= 1) s += __shfl_xor(s, off);
            float ls = m + logf(s);
            float* orow = out + (size_t)nodeW * 40;
            orow[c] = v0 - ls;
            orow[16 + c] = v1 - ls;
            if (v2ok) orow[32 + c] = v2 - ls;
        }
    }
}

// ---------------- launch ----------------

extern "C" void kernel_launch(void* const* d_in, const int* in_sizes, int n_in,
                              void* d_out, int out_size, void* d_ws, size_t ws_size,
                              hipStream_t stream) {
    const float* x  = (const float*)d_in[0];
    const int* ei   = (const int*)d_in[1];
    const float* W1 = (const float*)d_in[2];
    const float* b1 = (const float*)d_in[3];
    const float* Wh = (const float*)d_in[4];
    const float* bh = (const float*)d_in[5];
    const float* W2 = (const float*)d_in[6];
    const float* b2 = (const float*)d_in[7];
    float* out = (float*)d_out;

    const int N = in_sizes[0] / 64;
    const int E = in_sizes[1] / 2;
    const int nbuk = (N + 511) >> 9;         // 512-node buckets (needs N <= 131072)
    const int nTiles = (N + 15) / 16;
    const int Npad = nTiles * 16;            // zero-row index; buffers have Npad+1 rows

    const int* srcp = ei;
    const int* dstp = ei + E;

    size_t off = 0;
    auto alloc = [&](size_t bytes) {
        size_t o = off;
        off = (off + bytes + 255) & ~(size_t)255;
        return o;
    };
    char* ws = (char*)d_ws;
    int*      cntg    = (int*)(ws + alloc(256 * 4));
    int*      row_ptr = (int*)(ws + alloc((size_t)(N + 1) * 4));
    float*    dinv    = (float*)(ws + alloc((size_t)N * 4));
    int*      col     = (int*)(ws + alloc((size_t)E * 4));
    unsigned* ebuf    = (unsigned*)(ws + alloc((size_t)nbuk * BCAP * 4));
    unsigned short* wp1  = (unsigned short*)(ws + alloc(4096 * 2));
    unsigned short* wph  = (unsigned short*)(ws + alloc(4096 * 2));
    unsigned short* wp2  = (unsigned short*)(ws + alloc(3072 * 2));
    unsigned short* xb   = (unsigned short*)(ws + alloc((size_t)(Npad + 1) * 64 * 2));
    unsigned short* gA   = (unsigned short*)(ws + alloc((size_t)(Npad + 1) * 64 * 2));
    unsigned short* gB   = (unsigned short*)(ws + alloc((size_t)(Npad + 1) * 64 * 2));
    (void)ws_size;

    hipMemsetAsync(cntg, 0, 256 * 4, stream);

    const int ebGrid = (E + 256 * EPT - 1) / (256 * EPT);
    scat1_kernel<<<ebGrid, 256, 0, stream>>>(srcp, dstp, cntg, ebuf, E);
    build_kernel<<<nbuk, 256, 0, stream>>>(ebuf, cntg, row_ptr, col, dinv, N, E);

    const int n4 = N * 16;   // float4 groups (16 per 64-ch row)
    cvtpack_kernel<<<16 + (n4 + 255) / 256, 256, 0, stream>>>(x, xb, n4, Npad, dinv,
                                                              W1, Wh, W2, wp1, wph, wp2);

    // layer 1: xb -> gA     (agg + GEMM fused)
    fused_relu_kernel<<<nTiles, 256, 0, stream>>>(xb, row_ptr, col, dinv, wp1, b1, gA, N, Npad);
    // layer 2: gA -> gB
    fused_relu_kernel<<<nTiles, 256, 0, stream>>>(gA, row_ptr, col, dinv, wph, bh, gB, N, Npad);
    // layer 3: gB -> out (log-softmax, fp32)
    fused_lsm_kernel<<<nTiles, 256, 0, stream>>>(gB, row_ptr, col, dinv, wp2, b2, out, N, Npad);
}